// Round 2
// baseline (580.018 us; speedup 1.0000x reference)
//
#include <hip/hip_runtime.h>
#include <hip/hip_bf16.h>

typedef __bf16 bf16x8 __attribute__((ext_vector_type(8)));
typedef float f32x4 __attribute__((ext_vector_type(4)));

// ---- problem constants: B=4, S=2048, E=1024, H=16, D=64 ----
// ws layout (bf16 element offsets)
constexpr size_t XQ_OFF = 0;                 // x bf16 [8192][1024] x3
constexpr size_t WQ_OFF = 25165824;          // W bf16 [1024][1024] x4
constexpr size_t Q_OFF  = 29360128;          // Q bf16 [bh][s][d]
constexpr size_t KK_OFF = 37748736;          // K bf16 [bh][s][d]
constexpr size_t VT_OFF = 46137344;          // V^T bf16 [bh][d][s]
constexpr size_t CTX_OFF= 54525952;          // ctx merged bf16 [8192][1024]

__device__ __forceinline__ void gload16(const void* g, void* s) {
    __builtin_amdgcn_global_load_lds((__attribute__((address_space(1))) void*)g,
                                     (__attribute__((address_space(3))) void*)s, 16, 0, 0);
}
#define WAIT_VM0()   asm volatile("s_waitcnt vmcnt(0)" ::: "memory")
#define WAIT_VM4()   asm volatile("s_waitcnt vmcnt(4)" ::: "memory")
#define WAIT_LGKM0() asm volatile("s_waitcnt lgkmcnt(0)" ::: "memory")
#define BAR()        __builtin_amdgcn_s_barrier()

// ---------------- convert fp32 -> bf16 into ws ----------------
__global__ __launch_bounds__(256) void convert_k(
    const float* __restrict__ q, const float* __restrict__ k, const float* __restrict__ v,
    const float* __restrict__ Wq, const float* __restrict__ Wk, const float* __restrict__ Wv,
    const float* __restrict__ Wo, __bf16* __restrict__ ws) {
    int id = blockIdx.x * 256 + threadIdx.x;     // one 8-elem chunk per thread
    const int NX = 1048576;                      // chunks per X
    const int NW = 131072;                       // chunks per W
    const float* src; size_t dst; int local;
    if (id < 3 * NX) {
        int z = id / NX; local = id - z * NX;
        src = (z == 0) ? q : ((z == 1) ? k : v);
        dst = XQ_OFF + (size_t)z * 8388608;
    } else {
        int i2 = id - 3 * NX;
        int z = i2 / NW; local = i2 - z * NW;
        src = (z == 0) ? Wq : ((z == 1) ? Wk : ((z == 2) ? Wv : Wo));
        dst = WQ_OFF + (size_t)z * 1048576;
    }
    const float4* s4 = (const float4*)(src + (size_t)local * 8);
    float4 a = s4[0], b = s4[1];
    bf16x8 o;
    o[0]=(__bf16)a.x; o[1]=(__bf16)a.y; o[2]=(__bf16)a.z; o[3]=(__bf16)a.w;
    o[4]=(__bf16)b.x; o[5]=(__bf16)b.y; o[6]=(__bf16)b.z; o[7]=(__bf16)b.w;
    *(bf16x8*)(ws + dst + (size_t)local * 8) = o;
}

// ---------------- GEMM  C = A @ B^T (+bias), 128x128/BK32, 2-phase dbuf ----------------
template<int MODE>
__global__ __launch_bounds__(256) void gemm_k(
    __bf16* __restrict__ ws,
    const float* __restrict__ bq, const float* __restrict__ bk,
    const float* __restrict__ bv, const float* __restrict__ bo,
    float* __restrict__ out) {
    const int K = 1024;
    // XCD-chunked bijective swizzle (grid x=64, y=8, z = MODE?1:3)
    unsigned n = blockIdx.x + 64u * (blockIdx.y + 8u * blockIdx.z);
    unsigned cpx = (MODE == 0) ? 192u : 64u;
    unsigned m_ = (n & 7u) * cpx + (n >> 3);
    unsigned bx = m_ & 63u;
    unsigned rest = m_ >> 6;
    unsigned by = rest & 7u;
    unsigned bz = rest >> 3;

    int z = (int)bz;
    const __bf16* A; const __bf16* Bm; const float* bias;
    if (MODE == 0) {
        A    = ws + XQ_OFF + (size_t)z * 8388608;
        Bm   = ws + WQ_OFF + (size_t)z * 1048576;
        bias = (z == 0) ? bq : ((z == 1) ? bk : bv);
    } else {
        A    = ws + CTX_OFF;
        Bm   = ws + WQ_OFF + (size_t)3 * 1048576;
        bias = bo;
    }
    int row0 = (int)bx * 128, col0 = (int)by * 128;
    __shared__ __align__(16) __bf16 As[2][128 * 32];
    __shared__ __align__(16) __bf16 Bs[2][128 * 32];
    int t = threadIdx.x, lane = t & 63, w = t >> 6;
    int wr = w >> 1, wc = w & 1;
    f32x4 acc[4][4];
#pragma unroll
    for (int i = 0; i < 4; ++i)
#pragma unroll
        for (int j = 0; j < 4; ++j) acc[i][j] = (f32x4){0.f, 0.f, 0.f, 0.f};

    auto stage = [&](int buf, int kt) {
#pragma unroll
        for (int i = 0; i < 2; ++i) {
            int e = ((i * 4 + w) * 64 + lane) * 8;   // linear chunk, wave-uniform base + lane*16
            int r = e >> 5, c = e & 31;
            gload16(A  + (size_t)(row0 + r) * K + kt + c, &As[buf][e]);
            gload16(Bm + (size_t)(col0 + r) * K + kt + c, &Bs[buf][e]);
        }
    };

    stage(0, 0);
    int cur = 0;
    for (int kt = 0; kt < K; kt += 32) {
        bool nx = kt + 32 < K;
        if (nx) { stage(cur ^ 1, kt + 32); WAIT_VM4(); }
        else    { WAIT_VM0(); }
        BAR();
        const __bf16* Ac = As[cur];
        const __bf16* Bc = Bs[cur];
        bf16x8 af[4], bfr[4];
#pragma unroll
        for (int f = 0; f < 4; ++f) {
            af[f]  = *(const bf16x8*)&Ac[(wr * 64 + f * 16 + (lane & 15)) * 32 + (lane >> 4) * 8];
            bfr[f] = *(const bf16x8*)&Bc[(wc * 64 + f * 16 + (lane & 15)) * 32 + (lane >> 4) * 8];
        }
#pragma unroll
        for (int fr = 0; fr < 4; ++fr)
#pragma unroll
            for (int fc = 0; fc < 4; ++fc)
                acc[fr][fc] = __builtin_amdgcn_mfma_f32_16x16x32_bf16(af[fr], bfr[fc], acc[fr][fc], 0, 0, 0);
        WAIT_LGKM0();
        BAR();
        cur ^= 1;
    }

    if (MODE == 0) {
        __bf16* dqk = ws + Q_OFF + (size_t)z * 8388608;  // z=0 -> Q, z=1 -> K
        __bf16* dvt = ws + VT_OFF;
#pragma unroll
        for (int fr = 0; fr < 4; ++fr)
#pragma unroll
            for (int fc = 0; fc < 4; ++fc)
#pragma unroll
                for (int r = 0; r < 4; ++r) {
                    int m = row0 + wr * 64 + fr * 16 + ((lane >> 4) << 2) + r;
                    int nn = col0 + wc * 64 + fc * 16 + (lane & 15);
                    float val = acc[fr][fc][r] + bias[nn];
                    int bb = m >> 11, s = m & 2047, h = nn >> 6, d = nn & 63;
                    size_t bh = (size_t)bb * 16 + h;
                    if (z < 2) dqk[bh * 131072 + (size_t)s * 64 + d] = (__bf16)val;
                    else       dvt[bh * 131072 + (size_t)d * 2048 + s] = (__bf16)val;
                }
    } else {
#pragma unroll
        for (int fr = 0; fr < 4; ++fr)
#pragma unroll
            for (int fc = 0; fc < 4; ++fc)
#pragma unroll
                for (int r = 0; r < 4; ++r) {
                    int m = row0 + wr * 64 + fr * 16 + ((lane >> 4) << 2) + r;
                    int nn = col0 + wc * 64 + fc * 16 + (lane & 15);
                    out[(size_t)m * 1024 + nn] = acc[fr][fc][r] + bias[nn];
                }
    }
}

// ---------------- fused attention: QBLK=128, 8 waves, 2-phase dbuf K/V ----------------
__global__ __launch_bounds__(512) void attn_k(const __bf16* __restrict__ ws,
                                              __bf16* __restrict__ wsw,
                                              float* __restrict__ wout) {
    const __bf16* Qp  = ws + Q_OFF;
    const __bf16* Kp  = ws + KK_OFF;
    const __bf16* Vtp = ws + VT_OFF;
    __bf16* ctx = wsw + CTX_OFF;

    // XCD swizzle: XCD k owns bh in [8k, 8k+8) -> K/V working set ~4MB = one L2
    unsigned n = blockIdx.x + 16u * blockIdx.y;
    int bh = (int)((n & 7u) * 8u + ((n >> 3) >> 4));
    int q0 = (int)((n >> 3) & 15u) * 128;

    int t = threadIdx.x, lane = t & 63, w = t >> 6, g = lane >> 4;
    __shared__ __align__(16) __bf16 QP[128 * 64];       // Q tile, then reused as P tile
    __shared__ __align__(16) __bf16 Ks[2][64 * 64];
    __shared__ __align__(16) __bf16 Vts[2][64 * 64];
    const __bf16* Qb = Qp  + (size_t)bh * 131072;
    const __bf16* Kb = Kp  + (size_t)bh * 131072;
    const __bf16* Vb = Vtp + (size_t)bh * 131072;
    const float SCALE = 0.125f;

    // stage Q: linear LDS dest, chunk-swizzled global source (rule #21)
#pragma unroll
    for (int i = 0; i < 2; ++i) {
        int ch = t + 512 * i, r = ch >> 3, c8 = ch & 7;
        gload16(Qb + (size_t)(q0 + r) * 64 + ((c8 ^ (r & 7)) << 3), &QP[ch * 8]);
    }
    WAIT_VM0(); BAR();
    int qrow = w * 16 + (lane & 15);
    bf16x8 aq0 = *(const bf16x8*)((const char*)QP + qrow * 128 + ((g * 16) ^ ((qrow & 7) << 4)));
    bf16x8 aq1 = *(const bf16x8*)((const char*)QP + qrow * 128 + (((4 + g) * 16) ^ ((qrow & 7) << 4)));

    // ---- pass 1: row sums of exp ----
    {
        int r = t >> 3, c8 = t & 7;
        gload16(Kb + (size_t)r * 64 + ((c8 ^ (r & 7)) << 3), &Ks[0][t * 8]);
    }
    WAIT_VM0(); BAR();
    float rs[4] = {0.f, 0.f, 0.f, 0.f};
    int cur = 0;
    for (int kt = 0; kt < 2048; kt += 64) {
        bool nx = kt < 1984;
        if (nx) {
            int r = t >> 3, c8 = t & 7;
            gload16(Kb + (size_t)(kt + 64 + r) * 64 + ((c8 ^ (r & 7)) << 3), &Ks[cur ^ 1][t * 8]);
        }
        const __bf16* Kc = Ks[cur];
#pragma unroll
        for (int kc = 0; kc < 4; ++kc) {
            int krow = kc * 16 + (lane & 15);
            bf16x8 b0 = *(const bf16x8*)((const char*)Kc + krow * 128 + ((g * 16) ^ ((krow & 7) << 4)));
            bf16x8 b1 = *(const bf16x8*)((const char*)Kc + krow * 128 + (((4 + g) * 16) ^ ((krow & 7) << 4)));
            f32x4 s = (f32x4){0.f, 0.f, 0.f, 0.f};
            s = __builtin_amdgcn_mfma_f32_16x16x32_bf16(aq0, b0, s, 0, 0, 0);
            s = __builtin_amdgcn_mfma_f32_16x16x32_bf16(aq1, b1, s, 0, 0, 0);
#pragma unroll
            for (int r4 = 0; r4 < 4; ++r4) rs[r4] += __expf(s[r4] * SCALE);
        }
        WAIT_LGKM0();
        if (nx) WAIT_VM0();
        BAR();
        cur ^= 1;
    }
#pragma unroll
    for (int m = 1; m < 16; m <<= 1)
#pragma unroll
        for (int r4 = 0; r4 < 4; ++r4) rs[r4] += __shfl_xor(rs[r4], m);
    float rinv[4];
#pragma unroll
    for (int r4 = 0; r4 < 4; ++r4) rinv[r4] = 1.f / rs[r4];

    // ---- pass 2: normalized weights + P@V ----
    {
        int r = t >> 3, c8 = t & 7;
        gload16(Kb + (size_t)r * 64   + ((c8 ^ (r & 7)) << 3), &Ks[0][t * 8]);
        gload16(Vb + (size_t)r * 2048 + ((c8 ^ (r & 7)) << 3), &Vts[0][t * 8]);
    }
    WAIT_VM0(); BAR();
    cur = 0;
    f32x4 cacc[4];
#pragma unroll
    for (int i = 0; i < 4; ++i) cacc[i] = (f32x4){0.f, 0.f, 0.f, 0.f};

    for (int kt = 0; kt < 2048; kt += 64) {
        bool nx = kt < 1984;
        if (nx) {
            int r = t >> 3, c8 = t & 7;
            gload16(Kb + (size_t)(kt + 64 + r) * 64 + ((c8 ^ (r & 7)) << 3), &Ks[cur ^ 1][t * 8]);
            gload16(Vb + (size_t)r * 2048 + (kt + 64) + ((c8 ^ (r & 7)) << 3), &Vts[cur ^ 1][t * 8]);
        }
        const __bf16* Kc = Ks[cur];
        const __bf16* Vc = Vts[cur];
#pragma unroll
        for (int kc = 0; kc < 4; ++kc) {
            int krow = kc * 16 + (lane & 15);
            bf16x8 b0 = *(const bf16x8*)((const char*)Kc + krow * 128 + ((g * 16) ^ ((krow & 7) << 4)));
            bf16x8 b1 = *(const bf16x8*)((const char*)Kc + krow * 128 + (((4 + g) * 16) ^ ((krow & 7) << 4)));
            f32x4 s = (f32x4){0.f, 0.f, 0.f, 0.f};
            s = __builtin_amdgcn_mfma_f32_16x16x32_bf16(aq0, b0, s, 0, 0, 0);
            s = __builtin_amdgcn_mfma_f32_16x16x32_bf16(aq1, b1, s, 0, 0, 0);
#pragma unroll
            for (int r4 = 0; r4 < 4; ++r4) {
                float e = __expf(s[r4] * SCALE) * rinv[r4];
                int prow = w * 16 + (g << 2) + r4;
                int pcol = kc * 16 + (lane & 15);
                *(__bf16*)((char*)QP + prow * 128 + ((pcol * 2) ^ ((prow & 7) << 4))) = (__bf16)e;
            }
        }
        WAIT_LGKM0();
        __builtin_amdgcn_sched_barrier(0);
        BAR();
        // weights store: 2x bf16x8 per thread -> 4x float4, fully coalesced
#pragma unroll
        for (int i = 0; i < 2; ++i) {
            int ch = t + 512 * i, row = ch >> 3, c8 = ch & 7;
            bf16x8 p = *(const bf16x8*)((const char*)QP + row * 128 + ((c8 * 16) ^ ((row & 7) << 4)));
            f32x4 lo = (f32x4){(float)p[0], (float)p[1], (float)p[2], (float)p[3]};
            f32x4 hi = (f32x4){(float)p[4], (float)p[5], (float)p[6], (float)p[7]};
            float* dst = wout + ((size_t)bh * 2048 + q0 + row) * 2048 + kt + c8 * 8;
            *(f32x4*)dst = lo;
            *(f32x4*)(dst + 4) = hi;
        }
        // P @ V
        int arow = w * 16 + (lane & 15);
#pragma unroll
        for (int ks = 0; ks < 2; ++ks) {
            bf16x8 ap = *(const bf16x8*)((const char*)QP + arow * 128 + ((ks * 64 + g * 16) ^ ((arow & 7) << 4)));
#pragma unroll
            for (int dc = 0; dc < 4; ++dc) {
                int vrow = dc * 16 + (lane & 15);
                bf16x8 bv = *(const bf16x8*)((const char*)Vc + vrow * 128 + ((ks * 64 + g * 16) ^ ((vrow & 7) << 4)));
                cacc[dc] = __builtin_amdgcn_mfma_f32_16x16x32_bf16(ap, bv, cacc[dc], 0, 0, 0);
            }
        }
        WAIT_LGKM0();
        if (nx) WAIT_VM0();
        BAR();
        cur ^= 1;
    }

    // epilogue: ctx merged [b*2048+q][h*64+d] bf16
    int bb = bh >> 4, h = bh & 15;
#pragma unroll
    for (int dc = 0; dc < 4; ++dc)
#pragma unroll
        for (int r4 = 0; r4 < 4; ++r4) {
            int qg = q0 + w * 16 + (g << 2) + r4;
            int d = dc * 16 + (lane & 15);
            ctx[((size_t)bb * 2048 + qg) * 1024 + h * 64 + d] = (__bf16)cacc[dc][r4];
        }
}

extern "C" void kernel_launch(void* const* d_in, const int* in_sizes, int n_in,
                              void* d_out, int out_size, void* d_ws, size_t ws_size,
                              hipStream_t stream) {
    const float* q  = (const float*)d_in[0];
    const float* k  = (const float*)d_in[1];
    const float* v  = (const float*)d_in[2];
    const float* Wq = (const float*)d_in[3];
    const float* bq = (const float*)d_in[4];
    const float* Wk = (const float*)d_in[5];
    const float* bk = (const float*)d_in[6];
    const float* Wv = (const float*)d_in[7];
    const float* bv = (const float*)d_in[8];
    const float* Wo = (const float*)d_in[9];
    const float* bo = (const float*)d_in[10];
    __bf16* ws = (__bf16*)d_ws;
    float* out  = (float*)d_out;          // [8192][1024] fp32
    float* wout = out + 8388608;          // weights [4][16][2048][2048] fp32

    convert_k<<<dim3(14336), dim3(256), 0, stream>>>(q, k, v, Wq, Wk, Wv, Wo, ws);
    gemm_k<0><<<dim3(64, 8, 3), dim3(256), 0, stream>>>(ws, bq, bk, bv, bo, out);
    attn_k<<<dim3(16, 64), dim3(512), 0, stream>>>(ws, ws, wout);
    gemm_k<1><<<dim3(64, 8, 1), dim3(256), 0, stream>>>(ws, bq, bk, bv, bo, out);
}

// Round 3
// 542.447 us; speedup vs baseline: 1.0693x; 1.0693x over previous
//
#include <hip/hip_runtime.h>
#include <hip/hip_bf16.h>

typedef __bf16 bf16x8 __attribute__((ext_vector_type(8)));
typedef float f32x4 __attribute__((ext_vector_type(4)));

// ---- problem constants: B=4, S=2048, E=1024, H=16, D=64 ----
// ws layout (bf16 element offsets)
constexpr size_t XQ_OFF = 0;                 // x bf16 [8192][1024] x3 ; later reused as f32 rowsums [64][2048]
constexpr size_t WQ_OFF = 25165824;          // W bf16 [1024][1024] x4
constexpr size_t Q_OFF  = 29360128;          // Q bf16 [bh][s][d]
constexpr size_t KK_OFF = 37748736;          // K bf16 [bh][s][d]
constexpr size_t VT_OFF = 46137344;          // V^T bf16 [bh][d][s]
constexpr size_t CTX_OFF= 54525952;          // ctx merged bf16 [8192][1024]

__device__ __forceinline__ void gload16(const void* g, void* s) {
    __builtin_amdgcn_global_load_lds((__attribute__((address_space(1))) void*)g,
                                     (__attribute__((address_space(3))) void*)s, 16, 0, 0);
}
#define WAIT_VM0()   asm volatile("s_waitcnt vmcnt(0)" ::: "memory")
#define WAIT_VM4()   asm volatile("s_waitcnt vmcnt(4)" ::: "memory")
#define WAIT_VM8()   asm volatile("s_waitcnt vmcnt(8)" ::: "memory")
#define WAIT_LGKM0() asm volatile("s_waitcnt lgkmcnt(0)" ::: "memory")
#define BAR()        __builtin_amdgcn_s_barrier()

// ---------------- convert fp32 -> bf16 into ws ----------------
__global__ __launch_bounds__(256) void convert_k(
    const float* __restrict__ q, const float* __restrict__ k, const float* __restrict__ v,
    const float* __restrict__ Wq, const float* __restrict__ Wk, const float* __restrict__ Wv,
    const float* __restrict__ Wo, __bf16* __restrict__ ws) {
    int id = blockIdx.x * 256 + threadIdx.x;     // one 8-elem chunk per thread
    const int NX = 1048576;
    const int NW = 131072;
    const float* src; size_t dst; int local;
    if (id < 3 * NX) {
        int z = id / NX; local = id - z * NX;
        src = (z == 0) ? q : ((z == 1) ? k : v);
        dst = XQ_OFF + (size_t)z * 8388608;
    } else {
        int i2 = id - 3 * NX;
        int z = i2 / NW; local = i2 - z * NW;
        src = (z == 0) ? Wq : ((z == 1) ? Wk : ((z == 2) ? Wv : Wo));
        dst = WQ_OFF + (size_t)z * 1048576;
    }
    const float4* s4 = (const float4*)(src + (size_t)local * 8);
    float4 a = s4[0], b = s4[1];
    bf16x8 o;
    o[0]=(__bf16)a.x; o[1]=(__bf16)a.y; o[2]=(__bf16)a.z; o[3]=(__bf16)a.w;
    o[4]=(__bf16)b.x; o[5]=(__bf16)b.y; o[6]=(__bf16)b.z; o[7]=(__bf16)b.w;
    *(bf16x8*)(ws + dst + (size_t)local * 8) = o;
}

// ---------------- GEMM  C = A @ B^T (+bias), 128x128/BK32, 2-phase dbuf ----------------
template<int MODE>
__global__ __launch_bounds__(256) void gemm_k(
    __bf16* __restrict__ ws,
    const float* __restrict__ bq, const float* __restrict__ bk,
    const float* __restrict__ bv, const float* __restrict__ bo,
    float* __restrict__ out) {
    const int K = 1024;
    unsigned n = blockIdx.x + 64u * (blockIdx.y + 8u * blockIdx.z);
    unsigned cpx = (MODE == 0) ? 192u : 64u;
    unsigned m_ = (n & 7u) * cpx + (n >> 3);
    unsigned bx = m_ & 63u;
    unsigned rest = m_ >> 6;
    unsigned by = rest & 7u;
    unsigned bz = rest >> 3;

    int z = (int)bz;
    const __bf16* A; const __bf16* Bm; const float* bias;
    if (MODE == 0) {
        A    = ws + XQ_OFF + (size_t)z * 8388608;
        Bm   = ws + WQ_OFF + (size_t)z * 1048576;
        bias = (z == 0) ? bq : ((z == 1) ? bk : bv);
    } else {
        A    = ws + CTX_OFF;
        Bm   = ws + WQ_OFF + (size_t)3 * 1048576;
        bias = bo;
    }
    int row0 = (int)bx * 128, col0 = (int)by * 128;
    __shared__ __align__(16) __bf16 As[2][128 * 32];
    __shared__ __align__(16) __bf16 Bs[2][128 * 32];
    int t = threadIdx.x, lane = t & 63, w = t >> 6;
    int wr = w >> 1, wc = w & 1;
    f32x4 acc[4][4];
#pragma unroll
    for (int i = 0; i < 4; ++i)
#pragma unroll
        for (int j = 0; j < 4; ++j) acc[i][j] = (f32x4){0.f, 0.f, 0.f, 0.f};

    auto stage = [&](int buf, int kt) {
#pragma unroll
        for (int i = 0; i < 2; ++i) {
            int e = ((i * 4 + w) * 64 + lane) * 8;
            int r = e >> 5, c = e & 31;
            gload16(A  + (size_t)(row0 + r) * K + kt + c, &As[buf][e]);
            gload16(Bm + (size_t)(col0 + r) * K + kt + c, &Bs[buf][e]);
        }
    };

    stage(0, 0);
    int cur = 0;
    for (int kt = 0; kt < K; kt += 32) {
        bool nx = kt + 32 < K;
        if (nx) { stage(cur ^ 1, kt + 32); WAIT_VM4(); }
        else    { WAIT_VM0(); }
        BAR();
        const __bf16* Ac = As[cur];
        const __bf16* Bc = Bs[cur];
        bf16x8 af[4], bfr[4];
#pragma unroll
        for (int f = 0; f < 4; ++f) {
            af[f]  = *(const bf16x8*)&Ac[(wr * 64 + f * 16 + (lane & 15)) * 32 + (lane >> 4) * 8];
            bfr[f] = *(const bf16x8*)&Bc[(wc * 64 + f * 16 + (lane & 15)) * 32 + (lane >> 4) * 8];
        }
#pragma unroll
        for (int fr = 0; fr < 4; ++fr)
#pragma unroll
            for (int fc = 0; fc < 4; ++fc)
                acc[fr][fc] = __builtin_amdgcn_mfma_f32_16x16x32_bf16(af[fr], bfr[fc], acc[fr][fc], 0, 0, 0);
        WAIT_LGKM0();
        BAR();
        cur ^= 1;
    }

    if (MODE == 0) {
        __bf16* dqk = ws + Q_OFF + (size_t)z * 8388608;
        __bf16* dvt = ws + VT_OFF;
#pragma unroll
        for (int fr = 0; fr < 4; ++fr)
#pragma unroll
            for (int fc = 0; fc < 4; ++fc)
#pragma unroll
                for (int r = 0; r < 4; ++r) {
                    int m = row0 + wr * 64 + fr * 16 + ((lane >> 4) << 2) + r;
                    int nn = col0 + wc * 64 + fc * 16 + (lane & 15);
                    float val = acc[fr][fc][r] + bias[nn];
                    int bb = m >> 11, s = m & 2047, h = nn >> 6, d = nn & 63;
                    size_t bh = (size_t)bb * 16 + h;
                    if (z < 2) dqk[bh * 131072 + (size_t)s * 64 + d] = (__bf16)val;
                    else       dvt[bh * 131072 + (size_t)d * 2048 + s] = (__bf16)val;
                }
    } else {
#pragma unroll
        for (int fr = 0; fr < 4; ++fr)
#pragma unroll
            for (int fc = 0; fc < 4; ++fc)
#pragma unroll
                for (int r = 0; r < 4; ++r) {
                    int m = row0 + wr * 64 + fr * 16 + ((lane >> 4) << 2) + r;
                    int nn = col0 + wc * 64 + fc * 16 + (lane & 15);
                    out[(size_t)m * 1024 + nn] = acc[fr][fc][r] + bias[nn];
                }
    }
}

// ---------------- pass 1: rowsums of exp(QK^T/8), QBLK=256, Q in regs ----------------
__global__ __launch_bounds__(512) void rowsum_k(const __bf16* __restrict__ ws,
                                                float* __restrict__ rs_out) {
    // grid (8,64); XCD-chunked: XCD k owns bh [8k,8k+8)
    unsigned n = blockIdx.x + 8u * blockIdx.y;
    unsigned m = (n & 7u) * 64u + (n >> 3);
    int bh = (int)(m >> 3);
    int q0 = (int)(m & 7u) * 256;
    const __bf16* Qb = ws + Q_OFF  + (size_t)bh * 131072;
    const __bf16* Kb = ws + KK_OFF + (size_t)bh * 131072;
    __shared__ __align__(16) __bf16 Ks[2][64 * 64];
    int t = threadIdx.x, lane = t & 63, w = t >> 6, g = lane >> 4;
    const float SCALE = 0.125f;

    // Q fragments direct from global: wave owns rows [w*32, w*32+32)
    bf16x8 aq[2][2];
#pragma unroll
    for (int f = 0; f < 2; ++f) {
        int qr = q0 + w * 32 + f * 16 + (lane & 15);
        aq[f][0] = *(const bf16x8*)&Qb[(size_t)qr * 64 + g * 8];
        aq[f][1] = *(const bf16x8*)&Qb[(size_t)qr * 64 + 32 + g * 8];
    }

    { int r = t >> 3, c8 = t & 7;
      gload16(Kb + (size_t)r * 64 + ((c8 ^ (r & 7)) << 3), &Ks[0][t * 8]); }
    WAIT_VM0(); BAR();

    float rs[8] = {0.f,0.f,0.f,0.f,0.f,0.f,0.f,0.f};
    int cur = 0;
    for (int kt = 0; kt < 2048; kt += 64) {
        bool nx = kt < 1984;
        if (nx) {
            int r = t >> 3, c8 = t & 7;
            gload16(Kb + (size_t)(kt + 64 + r) * 64 + ((c8 ^ (r & 7)) << 3), &Ks[cur ^ 1][t * 8]);
        }
        const __bf16* Kc = Ks[cur];
        __builtin_amdgcn_s_setprio(1);
#pragma unroll
        for (int kc = 0; kc < 4; ++kc) {
            int krow = kc * 16 + (lane & 15);
            bf16x8 b0 = *(const bf16x8*)((const char*)Kc + krow * 128 + ((g * 16) ^ ((krow & 7) << 4)));
            bf16x8 b1 = *(const bf16x8*)((const char*)Kc + krow * 128 + (((4 + g) * 16) ^ ((krow & 7) << 4)));
#pragma unroll
            for (int f = 0; f < 2; ++f) {
                f32x4 s = (f32x4){0.f, 0.f, 0.f, 0.f};
                s = __builtin_amdgcn_mfma_f32_16x16x32_bf16(aq[f][0], b0, s, 0, 0, 0);
                s = __builtin_amdgcn_mfma_f32_16x16x32_bf16(aq[f][1], b1, s, 0, 0, 0);
#pragma unroll
                for (int r4 = 0; r4 < 4; ++r4) rs[f * 4 + r4] += __expf(s[r4] * SCALE);
            }
        }
        __builtin_amdgcn_s_setprio(0);
        WAIT_LGKM0();
        if (nx) WAIT_VM0();
        BAR();
        cur ^= 1;
    }
#pragma unroll
    for (int msk = 1; msk < 16; msk <<= 1)
#pragma unroll
        for (int i = 0; i < 8; ++i) rs[i] += __shfl_xor(rs[i], msk);
    if ((lane & 15) == 0) {
#pragma unroll
        for (int f = 0; f < 2; ++f)
#pragma unroll
            for (int r4 = 0; r4 < 4; ++r4)
                rs_out[(size_t)bh * 2048 + q0 + w * 32 + f * 16 + g * 4 + r4] = rs[f * 4 + r4];
    }
}

// ---------------- pass 2: weights + P@V, QBLK=256, counted vmcnt ----------------
__global__ __launch_bounds__(512) void attnw_k(const __bf16* __restrict__ ws,
                                               const float* __restrict__ rsf,
                                               __bf16* __restrict__ wsw,
                                               float* __restrict__ wout) {
    unsigned n = blockIdx.x + 8u * blockIdx.y;
    unsigned m = (n & 7u) * 64u + (n >> 3);
    int bh = (int)(m >> 3);
    int q0 = (int)(m & 7u) * 256;

    const __bf16* Qb = ws + Q_OFF  + (size_t)bh * 131072;
    const __bf16* Kb = ws + KK_OFF + (size_t)bh * 131072;
    const __bf16* Vb = ws + VT_OFF + (size_t)bh * 131072;
    __bf16* ctx = wsw + CTX_OFF;

    int t = threadIdx.x, lane = t & 63, w = t >> 6, g = lane >> 4;
    __shared__ __align__(16) __bf16 QP[256 * 64];     // Q tile then P tile (32KB)
    __shared__ __align__(16) __bf16 Ks[2][64 * 64];
    __shared__ __align__(16) __bf16 Vts[2][64 * 64];
    const float SCALE = 0.125f;

    // rinv for this thread's 8 rows
    float rinv[8];
#pragma unroll
    for (int f = 0; f < 2; ++f)
#pragma unroll
        for (int r4 = 0; r4 < 4; ++r4)
            rinv[f * 4 + r4] = 1.f / rsf[(size_t)bh * 2048 + q0 + w * 32 + f * 16 + g * 4 + r4];

    // stage Q (256x64): 2048 chunks, 4 per thread
#pragma unroll
    for (int i = 0; i < 4; ++i) {
        int ch = t + 512 * i, r = ch >> 3, c8 = ch & 7;
        gload16(Qb + (size_t)(q0 + r) * 64 + ((c8 ^ (r & 7)) << 3), &QP[ch * 8]);
    }
    WAIT_VM0(); BAR();
    bf16x8 aq[2][2];
#pragma unroll
    for (int f = 0; f < 2; ++f) {
        int qrow = w * 32 + f * 16 + (lane & 15);
        aq[f][0] = *(const bf16x8*)((const char*)QP + qrow * 128 + ((g * 16) ^ ((qrow & 7) << 4)));
        aq[f][1] = *(const bf16x8*)((const char*)QP + qrow * 128 + (((4 + g) * 16) ^ ((qrow & 7) << 4)));
    }
    WAIT_LGKM0(); BAR();   // all aq reads done before QP becomes P

    // prefetch first K/V tiles
    { int r = t >> 3, c8 = t & 7;
      gload16(Kb + (size_t)r * 64   + ((c8 ^ (r & 7)) << 3), &Ks[0][t * 8]);
      gload16(Vb + (size_t)r * 2048 + ((c8 ^ (r & 7)) << 3), &Vts[0][t * 8]); }
    WAIT_VM0(); BAR();

    f32x4 cacc[2][4];
#pragma unroll
    for (int f = 0; f < 2; ++f)
#pragma unroll
        for (int dc = 0; dc < 4; ++dc) cacc[f][dc] = (f32x4){0.f, 0.f, 0.f, 0.f};

    int cur = 0;
    for (int kt = 0; kt < 2048; kt += 64) {
        bool nx = kt < 1984;
        if (nx) {
            int r = t >> 3, c8 = t & 7;
            gload16(Kb + (size_t)(kt + 64 + r) * 64 + ((c8 ^ (r & 7)) << 3), &Ks[cur ^ 1][t * 8]);
            gload16(Vb + (size_t)r * 2048 + (kt + 64) + ((c8 ^ (r & 7)) << 3), &Vts[cur ^ 1][t * 8]);
        }
        const __bf16* Kc = Ks[cur];
        const __bf16* Vc = Vts[cur];
        // ---- QK^T + exp*rinv -> P in LDS ----
        __builtin_amdgcn_s_setprio(1);
#pragma unroll
        for (int kc = 0; kc < 4; ++kc) {
            int krow = kc * 16 + (lane & 15);
            bf16x8 b0 = *(const bf16x8*)((const char*)Kc + krow * 128 + ((g * 16) ^ ((krow & 7) << 4)));
            bf16x8 b1 = *(const bf16x8*)((const char*)Kc + krow * 128 + (((4 + g) * 16) ^ ((krow & 7) << 4)));
#pragma unroll
            for (int f = 0; f < 2; ++f) {
                f32x4 s = (f32x4){0.f, 0.f, 0.f, 0.f};
                s = __builtin_amdgcn_mfma_f32_16x16x32_bf16(aq[f][0], b0, s, 0, 0, 0);
                s = __builtin_amdgcn_mfma_f32_16x16x32_bf16(aq[f][1], b1, s, 0, 0, 0);
#pragma unroll
                for (int r4 = 0; r4 < 4; ++r4) {
                    float e = __expf(s[r4] * SCALE) * rinv[f * 4 + r4];
                    int prow = w * 32 + f * 16 + (g << 2) + r4;
                    int pcol = kc * 16 + (lane & 15);
                    *(__bf16*)((char*)QP + prow * 128 + ((pcol * 2) ^ ((prow & 7) << 4))) = (__bf16)e;
                }
            }
        }
        __builtin_amdgcn_s_setprio(0);
        WAIT_LGKM0();
        __builtin_amdgcn_sched_barrier(0);
        BAR();
        // ---- weights store: 4 chunks/thread, 2x f32x4 each ----
#pragma unroll
        for (int i = 0; i < 4; ++i) {
            int ch = t + 512 * i, row = ch >> 3, c8 = ch & 7;
            bf16x8 p = *(const bf16x8*)((const char*)QP + row * 128 + ((c8 * 16) ^ ((row & 7) << 4)));
            f32x4 lo = (f32x4){(float)p[0], (float)p[1], (float)p[2], (float)p[3]};
            f32x4 hi = (f32x4){(float)p[4], (float)p[5], (float)p[6], (float)p[7]};
            float* dst = wout + ((size_t)bh * 2048 + q0 + row) * 2048 + kt + c8 * 8;
            *(f32x4*)dst = lo;
            *(f32x4*)(dst + 4) = hi;
        }
        // ---- P @ V ----
        __builtin_amdgcn_s_setprio(1);
#pragma unroll
        for (int ks = 0; ks < 2; ++ks) {
            bf16x8 ap[2];
#pragma unroll
            for (int f = 0; f < 2; ++f) {
                int arow = w * 32 + f * 16 + (lane & 15);
                ap[f] = *(const bf16x8*)((const char*)QP + arow * 128 + ((ks * 64 + g * 16) ^ ((arow & 7) << 4)));
            }
#pragma unroll
            for (int dc = 0; dc < 4; ++dc) {
                int vrow = dc * 16 + (lane & 15);
                bf16x8 bv = *(const bf16x8*)((const char*)Vc + vrow * 128 + ((ks * 64 + g * 16) ^ ((vrow & 7) << 4)));
#pragma unroll
                for (int f = 0; f < 2; ++f)
                    cacc[f][dc] = __builtin_amdgcn_mfma_f32_16x16x32_bf16(ap[f], bv, cacc[f][dc], 0, 0, 0);
            }
        }
        __builtin_amdgcn_s_setprio(0);
        WAIT_LGKM0();
        WAIT_VM8();   // retire the 2 K/V prefetch gloads; 8 weight stores stay in flight
        BAR();
        cur ^= 1;
    }

    // epilogue: ctx merged [b*2048+q][h*64+d] bf16
    int bb = bh >> 4, h = bh & 15;
#pragma unroll
    for (int f = 0; f < 2; ++f)
#pragma unroll
        for (int dc = 0; dc < 4; ++dc)
#pragma unroll
            for (int r4 = 0; r4 < 4; ++r4) {
                int qg = q0 + w * 32 + f * 16 + (g << 2) + r4;
                int d = dc * 16 + (lane & 15);
                ctx[((size_t)bb * 2048 + qg) * 1024 + h * 64 + d] = (__bf16)cacc[f][dc][r4];
            }
}

extern "C" void kernel_launch(void* const* d_in, const int* in_sizes, int n_in,
                              void* d_out, int out_size, void* d_ws, size_t ws_size,
                              hipStream_t stream) {
    const float* q  = (const float*)d_in[0];
    const float* k  = (const float*)d_in[1];
    const float* v  = (const float*)d_in[2];
    const float* Wq = (const float*)d_in[3];
    const float* bq = (const float*)d_in[4];
    const float* Wk = (const float*)d_in[5];
    const float* bk = (const float*)d_in[6];
    const float* Wv = (const float*)d_in[7];
    const float* bv = (const float*)d_in[8];
    const float* Wo = (const float*)d_in[9];
    const float* bo = (const float*)d_in[10];
    __bf16* ws = (__bf16*)d_ws;
    float* out  = (float*)d_out;          // [8192][1024] fp32
    float* wout = out + 8388608;          // weights [4][16][2048][2048] fp32
    float* rsum = (float*)d_ws;           // reuse XQ region after gemm<0> (512KB)

    convert_k<<<dim3(14336), dim3(256), 0, stream>>>(q, k, v, Wq, Wk, Wv, Wo, ws);
    gemm_k<0><<<dim3(64, 8, 3), dim3(256), 0, stream>>>(ws, bq, bk, bv, bo, out);
    rowsum_k<<<dim3(8, 64), dim3(512), 0, stream>>>(ws, rsum);
    attnw_k<<<dim3(8, 64), dim3(512), 0, stream>>>(ws, rsum, ws, wout);
    gemm_k<1><<<dim3(64, 8, 1), dim3(256), 0, stream>>>(ws, bq, bk, bv, bo, out);
}